// Round 1
// baseline (530.648 us; speedup 1.0000x reference)
//
#include <hip/hip_runtime.h>

#define NB 8

struct K1Args {
  const float* x[4];
  float* expl[4];
  float* Z[4];
  int N[4];
  int ntiles[4];
};

struct K3Args {
  const float* x[4];
  const float* expl[4];
  const float* Z[4];
  float* outp[4];
  float* ctx[4];
  int N[4];
};

// K1: logits = sum_c x[b, src(g,c), n] * w_qk[c]; store exp(logit); atomic Z += sum exp
__global__ __launch_bounds__(128) void k1_logits(K1Args a, const float* __restrict__ wqk_all) {
  int lvl = blockIdx.z;
  if ((int)blockIdx.x >= a.ntiles[lvl]) return;
  int N = a.N[lvl];
  int bg = blockIdx.y;            // b*3+g
  int g = bg % 3, b = bg / 3;
  int n0 = blockIdx.x * 512 + (threadIdx.x << 2);
  float esum = 0.f;
  if (n0 < N) {
    const float* __restrict__ xb = a.x[lvl] + (size_t)b * 768 * N;
    const float* __restrict__ wqk = wqk_all + lvl * 256;
    float4 acc = make_float4(0.f, 0.f, 0.f, 0.f);
#pragma unroll 8
    for (int c = 0; c < 256; ++c) {
      int f = g * 256 + c;
      int s = (f % 3) * 256 + (f / 3);
      float4 v = *(const float4*)(xb + (size_t)s * N + n0);
      float w = wqk[c];
      acc.x = fmaf(v.x, w, acc.x);
      acc.y = fmaf(v.y, w, acc.y);
      acc.z = fmaf(v.z, w, acc.z);
      acc.w = fmaf(v.w, w, acc.w);
    }
    float4 e;
    e.x = __expf(acc.x); e.y = __expf(acc.y); e.z = __expf(acc.z); e.w = __expf(acc.w);
    *(float4*)(a.expl[lvl] + (size_t)bg * N + n0) = e;
    esum = e.x + e.y + e.z + e.w;
  }
  for (int o = 32; o; o >>= 1) esum += __shfl_xor(esum, o);
  __shared__ float sr[2];
  if ((threadIdx.x & 63) == 0) sr[threadIdx.x >> 6] = esum;
  __syncthreads();
  if (threadIdx.x == 0) atomicAdd(&a.Z[lvl][bg], sr[0] + sr[1]);
}

// K3: out_partial[b,c2,n] = sum_g x[src(g,c2),n]  (store to d_out)
//     ctx[b,g,c2] = (sum_n x[src(g,c2),n] * expl[b,g,n]) / Z[b,g]
__global__ __launch_bounds__(256) void k3_ctx_out(K3Args a) {
  int lvl = blockIdx.z;
  int N = a.N[lvl];
  int c2 = blockIdx.x, b = blockIdx.y;
  const float* __restrict__ xb = a.x[lvl] + (size_t)b * 768 * N;
  int f0 = c2, f1 = 256 + c2, f2 = 512 + c2;
  const float* __restrict__ r0 = xb + (size_t)((f0 % 3) * 256 + f0 / 3) * N;
  const float* __restrict__ r1 = xb + (size_t)((f1 % 3) * 256 + f1 / 3) * N;
  const float* __restrict__ r2 = xb + (size_t)((f2 % 3) * 256 + f2 / 3) * N;
  const float* __restrict__ e0 = a.expl[lvl] + (size_t)(b * 3 + 0) * N;
  const float* __restrict__ e1 = a.expl[lvl] + (size_t)(b * 3 + 1) * N;
  const float* __restrict__ e2 = a.expl[lvl] + (size_t)(b * 3 + 2) * N;
  float* __restrict__ o = a.outp[lvl] + ((size_t)b * 256 + c2) * N;
  float a0 = 0.f, a1 = 0.f, a2 = 0.f;
  for (int n = threadIdx.x << 2; n < N; n += 1024) {
    float4 v0 = *(const float4*)(r0 + n);
    float4 v1 = *(const float4*)(r1 + n);
    float4 v2 = *(const float4*)(r2 + n);
    float4 w0 = *(const float4*)(e0 + n);
    float4 w1 = *(const float4*)(e1 + n);
    float4 w2 = *(const float4*)(e2 + n);
    float4 ov;
    ov.x = v0.x + v1.x + v2.x;
    ov.y = v0.y + v1.y + v2.y;
    ov.z = v0.z + v1.z + v2.z;
    ov.w = v0.w + v1.w + v2.w;
    *(float4*)(o + n) = ov;
    a0 += v0.x * w0.x + v0.y * w0.y + v0.z * w0.z + v0.w * w0.w;
    a1 += v1.x * w1.x + v1.y * w1.y + v1.z * w1.z + v1.w * w1.w;
    a2 += v2.x * w2.x + v2.y * w2.y + v2.z * w2.z + v2.w * w2.w;
  }
  for (int o2 = 32; o2; o2 >>= 1) {
    a0 += __shfl_xor(a0, o2);
    a1 += __shfl_xor(a1, o2);
    a2 += __shfl_xor(a2, o2);
  }
  __shared__ float sr[3][4];
  int wv = threadIdx.x >> 6;
  if ((threadIdx.x & 63) == 0) { sr[0][wv] = a0; sr[1][wv] = a1; sr[2][wv] = a2; }
  __syncthreads();
  if (threadIdx.x == 0) {
    const float* Z = a.Z[lvl];
    float t0 = (sr[0][0] + sr[0][1] + sr[0][2] + sr[0][3]) / Z[b * 3 + 0];
    float t1 = (sr[1][0] + sr[1][1] + sr[1][2] + sr[1][3]) / Z[b * 3 + 1];
    float t2 = (sr[2][0] + sr[2][1] + sr[2][2] + sr[2][3]) / Z[b * 3 + 2];
    float* c = a.ctx[lvl];
    c[((size_t)b * 3 + 0) * 256 + c2] = t0;
    c[((size_t)b * 3 + 1) * 256 + c2] = t1;
    c[((size_t)b * 3 + 2) * 256 + c2] = t2;
  }
}

__device__ __forceinline__ float blk_sum256(float v, float* sr4) {
  for (int o = 32; o; o >>= 1) v += __shfl_xor(v, o);
  __syncthreads();
  if ((threadIdx.x & 63) == 0) sr4[threadIdx.x >> 6] = v;
  __syncthreads();
  return sr4[0] + sr4[1] + sr4[2] + sr4[3];
}

// K4: per (b,lvl): ct-MLP (LN+relu) and lvl-weight MLP (LN+relu+sigmoid),
//     add[b,c2] = sum_g ctxT[g,c2] * lvlw[g]
__global__ __launch_bounds__(256) void k4_mlp(
    const float* __restrict__ ctx_all,
    const float* __restrict__ ct_w1, const float* __restrict__ ct_b1,
    const float* __restrict__ ct_g,  const float* __restrict__ ct_be,
    const float* __restrict__ ct_w2, const float* __restrict__ ct_b2,
    const float* __restrict__ lw_w1, const float* __restrict__ lw_b1,
    const float* __restrict__ lw_g,  const float* __restrict__ lw_be,
    const float* __restrict__ lw_w2, const float* __restrict__ lw_b2,
    float* __restrict__ add_all) {
  int b = blockIdx.x, lvl = blockIdx.y;
  int t = threadIdx.x;
  const float* cin = ctx_all + ((size_t)lvl * NB + b) * 768;
  const float* w1 = ct_w1 + lvl * 64 * 256;
  const float* b1 = ct_b1 + lvl * 64;
  const float* cg = ct_g + lvl * 64;
  const float* cbe = ct_be + lvl * 64;
  const float* w2 = ct_w2 + lvl * 256 * 64;
  const float* b2 = ct_b2 + lvl * 256;
  const float* W1 = lw_w1 + (size_t)lvl * 768 * 768;
  const float* B1 = lw_b1 + lvl * 768;
  const float* Lg = lw_g + lvl * 768;
  const float* Lbe = lw_be + lvl * 768;
  const float* W2 = lw_w2 + lvl * 3 * 768;
  const float* B2 = lw_b2 + lvl * 3;
  float* addp = add_all + ((size_t)lvl * NB + b) * 256;

  __shared__ float sctx[768];
  __shared__ float sh1[3][64];
  __shared__ float sl1[768];
  __shared__ float slvlw[3];
  __shared__ float sr4[4];

  for (int i = t; i < 768; i += 256) sctx[i] = cin[i];
  __syncthreads();

  // ct fc1: h1[g,j] = ctx[g,:] . w1[j,:] + b1[j]
  if (t < 192) {
    int g = t >> 6, j = t & 63;
    float acc = b1[j];
    const float* w = w1 + j * 256;
    const float* c = sctx + g * 256;
#pragma unroll 4
    for (int k = 0; k < 256; ++k) acc = fmaf(c[k], w[k], acc);
    sh1[g][j] = acc;
  }
  __syncthreads();
  // LN(64)+relu per g (waves 0..2)
  int wv = t >> 6, ln = t & 63;
  if (wv < 3) {
    float v = sh1[wv][ln];
    float s = v;
    for (int o = 32; o; o >>= 1) s += __shfl_xor(s, o);
    float mean = s * (1.f / 64.f);
    float d = v - mean;
    float q = d * d;
    for (int o = 32; o; o >>= 1) q += __shfl_xor(q, o);
    float var = q * (1.f / 64.f);
    float y = d * rsqrtf(var + 1e-5f) * cg[ln] + cbe[ln];
    sh1[wv][ln] = fmaxf(y, 0.f);
  }
  // lw fc1: l1[j] = lvl_ctx . W1[j,:] + B1[j], 3 j per thread
  float l1v[3];
#pragma unroll
  for (int r = 0; r < 3; ++r) {
    int j = t + r * 256;
    float acc = B1[j];
    const float* w = W1 + (size_t)j * 768;
#pragma unroll 4
    for (int k = 0; k < 768; ++k) acc = fmaf(sctx[k], w[k], acc);
    l1v[r] = acc;
  }
  float S = blk_sum256(l1v[0] + l1v[1] + l1v[2], sr4);
  float mean = S * (1.f / 768.f);
  float q = 0.f;
#pragma unroll
  for (int r = 0; r < 3; ++r) { float d = l1v[r] - mean; q += d * d; }
  float var = blk_sum256(q, sr4) * (1.f / 768.f);
  float inv = rsqrtf(var + 1e-5f);
#pragma unroll
  for (int r = 0; r < 3; ++r) {
    int j = t + r * 256;
    float y = (l1v[r] - mean) * inv * Lg[j] + Lbe[j];
    sl1[j] = fmaxf(y, 0.f);
  }
  __syncthreads();
  if (wv < 3) {
    float acc = 0.f;
    for (int j = ln; j < 768; j += 64) acc = fmaf(sl1[j], W2[wv * 768 + j], acc);
    for (int o = 32; o; o >>= 1) acc += __shfl_xor(acc, o);
    if (ln == 0) slvlw[wv] = 1.f / (1.f + __expf(-(acc + B2[wv])));
  }
  __syncthreads();
  {
    int c2 = t;
    float a = 0.f;
#pragma unroll
    for (int g = 0; g < 3; ++g) {
      float acc = b2[c2];
      const float* w = w2 + c2 * 64;
#pragma unroll 4
      for (int j = 0; j < 64; ++j) acc = fmaf(sh1[g][j], w[j], acc);
      a += acc * slvlw[g];
    }
    addp[c2] = a;
  }
}

// K5: out[b,c2,:] += add[b,c2]
__global__ __launch_bounds__(256) void k5_add(float* __restrict__ out,
                                              const float* __restrict__ add, int lgN) {
  size_t f = ((size_t)blockIdx.x * 256 + threadIdx.x) << 2;
  int bc = (int)(f >> lgN);
  float a = add[bc];
  float4 v = *(float4*)(out + f);
  v.x += a; v.y += a; v.z += a; v.w += a;
  *(float4*)(out + f) = v;
}

extern "C" void kernel_launch(void* const* d_in, const int* in_sizes, int n_in,
                              void* d_out, int out_size, void* d_ws, size_t ws_size,
                              hipStream_t stream) {
  const float* gx[4] = {(const float*)d_in[0], (const float*)d_in[1],
                        (const float*)d_in[2], (const float*)d_in[3]};
  const float* x_last = (const float*)d_in[4];
  const float* w_qk = (const float*)d_in[5];
  // d_in[6] = b_qk: constant over softmax axis -> cancels, unused
  const float* ct_w1 = (const float*)d_in[7];
  const float* ct_b1 = (const float*)d_in[8];
  const float* ct_g  = (const float*)d_in[9];
  const float* ct_be = (const float*)d_in[10];
  const float* ct_w2 = (const float*)d_in[11];
  const float* ct_b2 = (const float*)d_in[12];
  const float* lw_w1 = (const float*)d_in[13];
  const float* lw_b1 = (const float*)d_in[14];
  const float* lw_g  = (const float*)d_in[15];
  const float* lw_be = (const float*)d_in[16];
  const float* lw_w2 = (const float*)d_in[17];
  const float* lw_b2 = (const float*)d_in[18];
  float* out = (float*)d_out;
  float* ws = (float*)d_ws;

  static const int Ns[4] = {16384, 4096, 1024, 256};
  static const size_t outOff[4] = {0, 33554432, 41943040, 44040192};
  static const size_t logOff[4] = {0, 393216, 491520, 516096};
  float* Zb   = ws + 522240;  // 4*24 floats
  float* ctxb = ws + 522336;  // 4*8*768 floats
  float* addb = ws + 546912;  // 4*8*256 floats

  hipMemsetAsync(Zb, 0, 96 * sizeof(float), stream);
  hipMemcpyAsync(out + 44564480, x_last, (size_t)131072 * sizeof(float),
                 hipMemcpyDeviceToDevice, stream);

  K1Args a1;
  K3Args a3;
  for (int i = 0; i < 4; ++i) {
    a1.x[i] = gx[i];
    a1.expl[i] = ws + logOff[i];
    a1.Z[i] = Zb + i * 24;
    a1.N[i] = Ns[i];
    int nt = Ns[i] / 512; if (nt < 1) nt = 1;
    a1.ntiles[i] = nt;
    a3.x[i] = gx[i];
    a3.expl[i] = ws + logOff[i];
    a3.Z[i] = Zb + i * 24;
    a3.outp[i] = out + outOff[i];
    a3.ctx[i] = ctxb + i * 6144;
    a3.N[i] = Ns[i];
  }

  dim3 g1(32, 24, 4);
  k1_logits<<<g1, dim3(128), 0, stream>>>(a1, w_qk);

  dim3 g3(256, NB, 4);
  k3_ctx_out<<<g3, dim3(256), 0, stream>>>(a3);

  dim3 g4(NB, 4);
  k4_mlp<<<g4, dim3(256), 0, stream>>>(ctxb, ct_w1, ct_b1, ct_g, ct_be, ct_w2, ct_b2,
                                       lw_w1, lw_b1, lw_g, lw_be, lw_w2, lw_b2, addb);

  static const int lgNs[4] = {14, 12, 10, 8};
  for (int i = 0; i < 4; ++i) {
    int blocks = (2048 * Ns[i]) / 1024;
    k5_add<<<dim3(blocks), dim3(256), 0, stream>>>(out + outOff[i], addb + i * 2048, lgNs[i]);
  }
}

// Round 3
// 467.694 us; speedup vs baseline: 1.1346x; 1.1346x over previous
//
#include <hip/hip_runtime.h>

#define NB 8
#define PART_STRIDE 522240  // floats per channel-half partial-logit buffer

typedef float f4 __attribute__((ext_vector_type(4)));

__device__ __forceinline__ f4 ntload(const float* p) {
  return __builtin_nontemporal_load((const f4*)p);
}
__device__ __forceinline__ void ntstore(float* p, f4 v) {
  __builtin_nontemporal_store(v, (f4*)p);
}

struct K1Args {
  const float* x[4];
  float* part;          // [2][522240] partial logits
  int N[4];
  int ntiles[4];        // N/512 (min 1)
  int logOff[4];
};

struct K2Args {
  float* part;          // in: two halves; out: expl in half 0
  float* zpart;         // [4][24][16]
  int N[4];
  int ntiles2[4];       // N/1024 (min 1)
  int logOff[4];
};

struct K3Args {
  const float* x[4];
  const float* expl;    // part half 0 (exp'd)
  const float* zpart;   // [4][24][16]
  float* outp[4];
  float* ctx[4];
  int N[4];
  int ntiles2[4];
  int logOff[4];
};

// K1: partial logits over a 128-channel half; two halves -> two buffers (deterministic, no atomics)
__global__ __launch_bounds__(128) void k1_partdot(K1Args a, const float* __restrict__ wqk_all) {
  int zz = blockIdx.z, lvl = zz >> 1, ch = zz & 1;
  if ((int)blockIdx.x >= a.ntiles[lvl]) return;
  int N = a.N[lvl];
  int bg = blockIdx.y, g = bg % 3, b = bg / 3;
  int n0 = blockIdx.x * 512 + (threadIdx.x << 2);
  if (n0 >= N) return;
  const float* __restrict__ xb = a.x[lvl] + (size_t)b * 768 * N;
  const float* __restrict__ wqk = wqk_all + lvl * 256 + ch * 128;
  f4 acc = {0.f, 0.f, 0.f, 0.f};
  int f0 = g * 256 + ch * 128;
#pragma unroll 8
  for (int i = 0; i < 128; ++i) {
    int f = f0 + i;
    int s = (f % 3) * 256 + f / 3;
    f4 v = ntload(xb + (size_t)s * N + n0);
    acc += v * wqk[i];
  }
  *(f4*)(a.part + (size_t)ch * PART_STRIDE + a.logOff[lvl] + (size_t)bg * N + n0) = acc;
}

// K2: expl = exp(part0 + part1) in place (half 0); per-(lvl,bg,tile) Z partial (deterministic)
__global__ __launch_bounds__(256) void k2_exp(K2Args a) {
  int lvl = blockIdx.z;
  if ((int)blockIdx.x >= a.ntiles2[lvl]) return;
  int N = a.N[lvl];
  int bg = blockIdx.y;
  int n0 = blockIdx.x * 1024 + (threadIdx.x << 2);
  float es = 0.f;
  if (n0 < N) {
    size_t off = (size_t)a.logOff[lvl] + (size_t)bg * N + n0;
    float* p0 = a.part + off;
    const float* p1 = a.part + PART_STRIDE + off;
    f4 v0 = *(const f4*)p0;
    f4 v1 = *(const f4*)p1;
    f4 s = v0 + v1;
    f4 e;
    e.x = __expf(s.x);
    e.y = __expf(s.y);
    e.z = __expf(s.z);
    e.w = __expf(s.w);
    *(f4*)p0 = e;
    es = e.x + e.y + e.z + e.w;
  }
  for (int o = 32; o; o >>= 1) es += __shfl_xor(es, o);
  __shared__ float sr[4];
  if ((threadIdx.x & 63) == 0) sr[threadIdx.x >> 6] = es;
  __syncthreads();
  if (threadIdx.x == 0)
    a.zpart[((size_t)lvl * 24 + bg) * 16 + blockIdx.x] = sr[0] + sr[1] + sr[2] + sr[3];
}

// K3: out_partial[b,c2,n] = sum_g x[src(g,c2),n] (nt store)
//     ctx[b,g,c2] = (sum_n x[src(g,c2),n] * expl[b,g,n]) / Z[b,g]
__global__ __launch_bounds__(256) void k3_ctx_out(K3Args a) {
  int lvl = blockIdx.z;
  int N = a.N[lvl];
  int c2 = blockIdx.x, b = blockIdx.y;
  const float* __restrict__ xb = a.x[lvl] + (size_t)b * 768 * N;
  int f0 = c2, f1 = 256 + c2, f2 = 512 + c2;
  const float* __restrict__ r0 = xb + (size_t)((f0 % 3) * 256 + f0 / 3) * N;
  const float* __restrict__ r1 = xb + (size_t)((f1 % 3) * 256 + f1 / 3) * N;
  const float* __restrict__ r2 = xb + (size_t)((f2 % 3) * 256 + f2 / 3) * N;
  const float* __restrict__ eb = a.expl + a.logOff[lvl];
  const float* __restrict__ e0 = eb + (size_t)(b * 3 + 0) * N;
  const float* __restrict__ e1 = eb + (size_t)(b * 3 + 1) * N;
  const float* __restrict__ e2 = eb + (size_t)(b * 3 + 2) * N;
  float* __restrict__ o = a.outp[lvl] + ((size_t)b * 256 + c2) * N;
  float a0 = 0.f, a1 = 0.f, a2 = 0.f;
#pragma unroll 2
  for (int n = threadIdx.x << 2; n < N; n += 1024) {
    f4 v0 = ntload(r0 + n);
    f4 v1 = ntload(r1 + n);
    f4 v2 = ntload(r2 + n);
    f4 w0 = *(const f4*)(e0 + n);
    f4 w1 = *(const f4*)(e1 + n);
    f4 w2 = *(const f4*)(e2 + n);
    f4 ov = v0 + v1 + v2;
    ntstore(o + n, ov);
    f4 p0 = v0 * w0, p1 = v1 * w1, p2 = v2 * w2;
    a0 += p0.x + p0.y + p0.z + p0.w;
    a1 += p1.x + p1.y + p1.z + p1.w;
    a2 += p2.x + p2.y + p2.z + p2.w;
  }
  for (int o2 = 32; o2; o2 >>= 1) {
    a0 += __shfl_xor(a0, o2);
    a1 += __shfl_xor(a1, o2);
    a2 += __shfl_xor(a2, o2);
  }
  __shared__ float sr[3][4];
  int wv = threadIdx.x >> 6;
  if ((threadIdx.x & 63) == 0) { sr[0][wv] = a0; sr[1][wv] = a1; sr[2][wv] = a2; }
  __syncthreads();
  if (threadIdx.x == 0) {
    const float* zp = a.zpart + (size_t)lvl * 24 * 16;
    int nt = a.ntiles2[lvl];
    float Z0 = 0.f, Z1 = 0.f, Z2 = 0.f;
    for (int t = 0; t < nt; ++t) {
      Z0 += zp[(b * 3 + 0) * 16 + t];
      Z1 += zp[(b * 3 + 1) * 16 + t];
      Z2 += zp[(b * 3 + 2) * 16 + t];
    }
    float t0 = (sr[0][0] + sr[0][1] + sr[0][2] + sr[0][3]) / Z0;
    float t1 = (sr[1][0] + sr[1][1] + sr[1][2] + sr[1][3]) / Z1;
    float t2 = (sr[2][0] + sr[2][1] + sr[2][2] + sr[2][3]) / Z2;
    float* c = a.ctx[lvl];
    c[((size_t)b * 3 + 0) * 256 + c2] = t0;
    c[((size_t)b * 3 + 1) * 256 + c2] = t1;
    c[((size_t)b * 3 + 2) * 256 + c2] = t2;
  }
}

__device__ __forceinline__ float blk_sum256(float v, float* sr4) {
  for (int o = 32; o; o >>= 1) v += __shfl_xor(v, o);
  __syncthreads();
  if ((threadIdx.x & 63) == 0) sr4[threadIdx.x >> 6] = v;
  __syncthreads();
  return sr4[0] + sr4[1] + sr4[2] + sr4[3];
}

// K4: per (b,lvl): ct-MLP (LN+relu) and lvl-weight MLP (LN+relu+sigmoid),
//     add[b,c2] = sum_g ctxT[g,c2] * lvlw[g]
__global__ __launch_bounds__(256) void k4_mlp(
    const float* __restrict__ ctx_all,
    const float* __restrict__ ct_w1, const float* __restrict__ ct_b1,
    const float* __restrict__ ct_g,  const float* __restrict__ ct_be,
    const float* __restrict__ ct_w2, const float* __restrict__ ct_b2,
    const float* __restrict__ lw_w1, const float* __restrict__ lw_b1,
    const float* __restrict__ lw_g,  const float* __restrict__ lw_be,
    const float* __restrict__ lw_w2, const float* __restrict__ lw_b2,
    float* __restrict__ add_all) {
  int b = blockIdx.x, lvl = blockIdx.y;
  int t = threadIdx.x;
  const float* cin = ctx_all + ((size_t)lvl * NB + b) * 768;
  const float* w1 = ct_w1 + lvl * 64 * 256;
  const float* b1 = ct_b1 + lvl * 64;
  const float* cg = ct_g + lvl * 64;
  const float* cbe = ct_be + lvl * 64;
  const float* w2 = ct_w2 + lvl * 256 * 64;
  const float* b2 = ct_b2 + lvl * 256;
  const float* W1 = lw_w1 + (size_t)lvl * 768 * 768;
  const float* B1 = lw_b1 + lvl * 768;
  const float* Lg = lw_g + lvl * 768;
  const float* Lbe = lw_be + lvl * 768;
  const float* W2 = lw_w2 + lvl * 3 * 768;
  const float* B2 = lw_b2 + lvl * 3;
  float* addp = add_all + ((size_t)lvl * NB + b) * 256;

  __shared__ float sctx[768];
  __shared__ float sh1[3][64];
  __shared__ float sl1[768];
  __shared__ float slvlw[3];
  __shared__ float sr4[4];

  for (int i = t; i < 768; i += 256) sctx[i] = cin[i];
  __syncthreads();

  if (t < 192) {
    int g = t >> 6, j = t & 63;
    float acc = b1[j];
    const float* w = w1 + j * 256;
    const float* c = sctx + g * 256;
#pragma unroll 4
    for (int k = 0; k < 256; ++k) acc = fmaf(c[k], w[k], acc);
    sh1[g][j] = acc;
  }
  __syncthreads();
  int wv = t >> 6, ln = t & 63;
  if (wv < 3) {
    float v = sh1[wv][ln];
    float s = v;
    for (int o = 32; o; o >>= 1) s += __shfl_xor(s, o);
    float mean = s * (1.f / 64.f);
    float d = v - mean;
    float q = d * d;
    for (int o = 32; o; o >>= 1) q += __shfl_xor(q, o);
    float var = q * (1.f / 64.f);
    float y = d * rsqrtf(var + 1e-5f) * cg[ln] + cbe[ln];
    sh1[wv][ln] = fmaxf(y, 0.f);
  }
  float l1v[3];
#pragma unroll
  for (int r = 0; r < 3; ++r) {
    int j = t + r * 256;
    float acc = B1[j];
    const float* w = W1 + (size_t)j * 768;
#pragma unroll 4
    for (int k = 0; k < 768; ++k) acc = fmaf(sctx[k], w[k], acc);
    l1v[r] = acc;
  }
  float S = blk_sum256(l1v[0] + l1v[1] + l1v[2], sr4);
  float mean = S * (1.f / 768.f);
  float q = 0.f;
#pragma unroll
  for (int r = 0; r < 3; ++r) { float d = l1v[r] - mean; q += d * d; }
  float var = blk_sum256(q, sr4) * (1.f / 768.f);
  float inv = rsqrtf(var + 1e-5f);
#pragma unroll
  for (int r = 0; r < 3; ++r) {
    int j = t + r * 256;
    float y = (l1v[r] - mean) * inv * Lg[j] + Lbe[j];
    sl1[j] = fmaxf(y, 0.f);
  }
  __syncthreads();
  if (wv < 3) {
    float acc = 0.f;
    for (int j = ln; j < 768; j += 64) acc = fmaf(sl1[j], W2[wv * 768 + j], acc);
    for (int o = 32; o; o >>= 1) acc += __shfl_xor(acc, o);
    if (ln == 0) slvlw[wv] = 1.f / (1.f + __expf(-(acc + B2[wv])));
  }
  __syncthreads();
  {
    int c2 = t;
    float a = 0.f;
#pragma unroll
    for (int g = 0; g < 3; ++g) {
      float acc = b2[c2];
      const float* w = w2 + c2 * 64;
#pragma unroll 4
      for (int j = 0; j < 64; ++j) acc = fmaf(sh1[g][j], w[j], acc);
      a += acc * slvlw[g];
    }
    addp[c2] = a;
  }
}

// K5: single launch over all 4 levels; out[b,c2,:] += add[b,c2]
__global__ __launch_bounds__(256) void k5_add(float* __restrict__ out,
                                              const float* __restrict__ add_all) {
  size_t f4i = (size_t)blockIdx.x * 256 + threadIdx.x;
  int lvl, lgN2;
  size_t base;
  if (f4i < 8388608)       { lvl = 0; base = 0;        lgN2 = 12; }
  else if (f4i < 10485760) { lvl = 1; base = 8388608;  lgN2 = 10; }
  else if (f4i < 11010048) { lvl = 2; base = 10485760; lgN2 = 8;  }
  else                     { lvl = 3; base = 11010048; lgN2 = 6;  }
  size_t lf4 = f4i - base;
  int bc = (int)(lf4 >> lgN2);
  float a = add_all[lvl * 2048 + bc];
  float* p = out + (f4i << 2);
  f4 v = ntload(p);
  v += a;
  ntstore(p, v);
}

extern "C" void kernel_launch(void* const* d_in, const int* in_sizes, int n_in,
                              void* d_out, int out_size, void* d_ws, size_t ws_size,
                              hipStream_t stream) {
  const float* gx[4] = {(const float*)d_in[0], (const float*)d_in[1],
                        (const float*)d_in[2], (const float*)d_in[3]};
  const float* x_last = (const float*)d_in[4];
  const float* w_qk = (const float*)d_in[5];
  // d_in[6] = b_qk: constant over softmax axis -> cancels, unused
  const float* ct_w1 = (const float*)d_in[7];
  const float* ct_b1 = (const float*)d_in[8];
  const float* ct_g  = (const float*)d_in[9];
  const float* ct_be = (const float*)d_in[10];
  const float* ct_w2 = (const float*)d_in[11];
  const float* ct_b2 = (const float*)d_in[12];
  const float* lw_w1 = (const float*)d_in[13];
  const float* lw_b1 = (const float*)d_in[14];
  const float* lw_g  = (const float*)d_in[15];
  const float* lw_be = (const float*)d_in[16];
  const float* lw_w2 = (const float*)d_in[17];
  const float* lw_b2 = (const float*)d_in[18];
  float* out = (float*)d_out;
  float* ws = (float*)d_ws;

  static const int Ns[4] = {16384, 4096, 1024, 256};
  static const int nt1[4] = {32, 8, 2, 1};    // N/512
  static const int nt2[4] = {16, 4, 1, 1};    // N/1024
  static const int logOff[4] = {0, 393216, 491520, 516096};
  static const size_t outOff[4] = {0, 33554432, 41943040, 44040192};

  float* partb = ws;                       // 2 * 522240
  float* zpart = ws + 2 * PART_STRIDE;     // 4*24*16 = 1536
  float* ctxb  = zpart + 1536;             // 4*8*768 = 24576
  float* addb  = ctxb + 24576;             // 4*8*256 = 8192

  hipMemcpyAsync(out + 44564480, x_last, (size_t)131072 * sizeof(float),
                 hipMemcpyDeviceToDevice, stream);

  K1Args a1;
  K2Args a2;
  K3Args a3;
  a1.part = partb;
  a2.part = partb;
  a2.zpart = zpart;
  a3.expl = partb;
  a3.zpart = zpart;
  for (int i = 0; i < 4; ++i) {
    a1.x[i] = gx[i];
    a1.N[i] = Ns[i];
    a1.ntiles[i] = nt1[i];
    a1.logOff[i] = logOff[i];
    a2.N[i] = Ns[i];
    a2.ntiles2[i] = nt2[i];
    a2.logOff[i] = logOff[i];
    a3.x[i] = gx[i];
    a3.outp[i] = out + outOff[i];
    a3.ctx[i] = ctxb + i * 6144;
    a3.N[i] = Ns[i];
    a3.ntiles2[i] = nt2[i];
    a3.logOff[i] = logOff[i];
  }

  k1_partdot<<<dim3(32, 24, 8), dim3(128), 0, stream>>>(a1, w_qk);
  k2_exp<<<dim3(16, 24, 4), dim3(256), 0, stream>>>(a2);
  k3_ctx_out<<<dim3(256, NB, 4), dim3(256), 0, stream>>>(a3);
  k4_mlp<<<dim3(NB, 4), dim3(256), 0, stream>>>(ctxb, ct_w1, ct_b1, ct_g, ct_be,
                                                ct_w2, ct_b2, lw_w1, lw_b1, lw_g,
                                                lw_be, lw_w2, lw_b2, addb);
  k5_add<<<dim3(43520), dim3(256), 0, stream>>>(out, addb);
}